// Round 1
// baseline (131.428 us; speedup 1.0000x reference)
//
#include <hip/hip_runtime.h>

#define EPSV 1e-5f

// ---------------- Kernel 1: adaptive avg pool + softmax(alpha) scale --------
// One block (256 threads) per (b, global-channel) row. Row staged in LDS.
__global__ __launch_bounds__(256) void pool_kernel(
    const float* __restrict__ s1, const float* __restrict__ s2,
    const float* __restrict__ s3, const float* __restrict__ alpha,
    float* __restrict__ fused) {
  __shared__ float row[5000];
  int rid = blockIdx.x;          // 0 .. 64*448-1
  int b = rid / 448;
  int cg = rid % 448;
  const float* src; int C, L, c, widx;
  if (cg < 256)      { src = s1; C = 256; L = 5000; c = cg;       widx = 0; }
  else if (cg < 384) { src = s2; C = 128; L = 2500; c = cg - 256; widx = 1; }
  else               { src = s3; C = 64;  L = 625;  c = cg - 384; widx = 2; }

  // softmax(alpha) (3 elements, cheap, L2-cached)
  float a0 = alpha[0], a1 = alpha[1], a2 = alpha[2];
  float mx = fmaxf(a0, fmaxf(a1, a2));
  float e0 = expf(a0 - mx), e1 = expf(a1 - mx), e2 = expf(a2 - mx);
  float wst = ((widx == 0) ? e0 : (widx == 1) ? e1 : e2) / (e0 + e1 + e2);

  const float* rowp = src + ((size_t)b * C + c) * L;
  for (int i = threadIdx.x; i < L; i += 256) row[i] = rowp[i];
  __syncthreads();

  int l = threadIdx.x;                       // 256 output positions
  int start = (l * L) >> 8;                  // floor(l*L/256)
  int end = ((l + 1) * L + 255) >> 8;        // ceil((l+1)*L/256)
  float s = 0.f;
  for (int i = start; i < end; ++i) s += row[i];
  fused[((size_t)b * 448 + cg) * 256 + l] = s / (float)(end - start) * wst;
}

// ---------------- Kernel 2: 2-bit weight quantization -----------------------
__global__ __launch_bounds__(256) void quant_kernel(
    const float* __restrict__ w, float* __restrict__ wq) {
  int o = blockIdx.x;            // 128 rows
  int t = threadIdx.x;
  const float* wr = w + o * 448;
  float m = 0.f;
  for (int c = t; c < 448; c += 256) m = fmaxf(m, fabsf(wr[c]));
  __shared__ float sm[4];
  for (int off = 32; off; off >>= 1) m = fmaxf(m, __shfl_down(m, off, 64));
  if ((t & 63) == 0) sm[t >> 6] = m;
  __syncthreads();
  m = fmaxf(fmaxf(sm[0], sm[1]), fmaxf(sm[2], sm[3]));
  float scale = fmaxf(m, 1e-8f);             // qp = 1 for 2-bit symmetric
  for (int c = t; c < 448; c += 256) {
    float q = rintf(wr[c] / scale);          // round-half-even == jnp.round
    q = fminf(fmaxf(q, -2.f), 1.f);
    wq[o * 448 + c] = q * scale;
  }
}

// ---------------- Kernel 3: fp32 tiled GEMM y[b] = wq @ fused[b] + bias -----
#define BM 64
#define BN 64
#define BK 16
__global__ __launch_bounds__(256) void gemm_kernel(
    const float* __restrict__ wq, const float* __restrict__ fused,
    const float* __restrict__ bias, float* __restrict__ y) {
  __shared__ float As[BK][BM + 4];   // [k][m]
  __shared__ float Bs[BK][BN + 4];   // [k][n]
  int b = blockIdx.z;
  int o0 = blockIdx.y * BM;
  int l0 = blockIdx.x * BN;
  const float* Bp = fused + (size_t)b * 448 * 256;
  int tid = threadIdx.x;
  int tx = tid & 15, ty = tid >> 4;
  float acc[4][4] = {};
  for (int c0 = 0; c0 < 448; c0 += BK) {
    {  // A tile: 64x16, 4 consecutive k per thread
      int m = tid >> 2;
      int k = (tid & 3) * 4;
      const float* p = wq + (o0 + m) * 448 + c0 + k;
      As[k][m] = p[0]; As[k + 1][m] = p[1]; As[k + 2][m] = p[2]; As[k + 3][m] = p[3];
    }
    {  // B tile: 16x64, coalesced rows
      #pragma unroll
      for (int i = 0; i < 4; ++i) {
        int e = tid + 256 * i;
        int n = e & 63, k = e >> 6;
        Bs[k][n] = Bp[(size_t)(c0 + k) * 256 + l0 + n];
      }
    }
    __syncthreads();
    #pragma unroll
    for (int k = 0; k < BK; ++k) {
      float a[4], bb[4];
      #pragma unroll
      for (int i = 0; i < 4; ++i) a[i] = As[k][ty * 4 + i];
      #pragma unroll
      for (int j = 0; j < 4; ++j) bb[j] = Bs[k][tx * 4 + j];
      #pragma unroll
      for (int i = 0; i < 4; ++i)
        #pragma unroll
        for (int j = 0; j < 4; ++j)
          acc[i][j] += a[i] * bb[j];
    }
    __syncthreads();
  }
  #pragma unroll
  for (int i = 0; i < 4; ++i) {
    float bv = bias[o0 + ty * 4 + i];
    #pragma unroll
    for (int j = 0; j < 4; ++j)
      y[((size_t)b * 128 + o0 + ty * 4 + i) * 256 + l0 + tx * 4 + j] = acc[i][j] + bv;
  }
}

// ---------------- Kernel 4: per-channel batch stats -------------------------
__global__ __launch_bounds__(256) void stats_kernel(
    const float* __restrict__ y, float* __restrict__ stats) {
  int o = blockIdx.x;            // 128 channels
  int l = threadIdx.x;           // 256 = L
  float s = 0.f, ss = 0.f;
  for (int b = 0; b < 64; ++b) {
    float v = y[((size_t)b * 128 + o) * 256 + l];
    s += v; ss += v * v;
  }
  __shared__ float sbuf[8];
  for (int off = 32; off; off >>= 1) {
    s += __shfl_down(s, off, 64);
    ss += __shfl_down(ss, off, 64);
  }
  if ((l & 63) == 0) { sbuf[l >> 6] = s; sbuf[4 + (l >> 6)] = ss; }
  __syncthreads();
  if (l == 0) {
    s = sbuf[0] + sbuf[1] + sbuf[2] + sbuf[3];
    ss = sbuf[4] + sbuf[5] + sbuf[6] + sbuf[7];
    float mean = s * (1.f / 16384.f);
    float var = ss * (1.f / 16384.f) - mean * mean;
    stats[o] = mean;
    stats[128 + o] = rsqrtf(var + EPSV);
  }
}

// ---------------- Kernel 5: BN apply + ELU + mean over L --------------------
__global__ __launch_bounds__(256) void final_kernel(
    const float* __restrict__ y, const float* __restrict__ stats,
    const float* __restrict__ gamma, const float* __restrict__ beta,
    float* __restrict__ out) {
  int bo = blockIdx.x;           // b*128 + o
  int o = bo & 127;
  int l = threadIdx.x;
  float mean = stats[o], rs = stats[128 + o];
  float g = gamma[o], bt = beta[o];
  float v = y[(size_t)bo * 256 + l];
  float yn = (v - mean) * rs * g + bt;
  float act = yn > 0.f ? yn : expm1f(yn);
  __shared__ float sbuf[4];
  for (int off = 32; off; off >>= 1) act += __shfl_down(act, off, 64);
  if ((l & 63) == 0) sbuf[l >> 6] = act;
  __syncthreads();
  if (l == 0) out[bo] = (sbuf[0] + sbuf[1] + sbuf[2] + sbuf[3]) * (1.f / 256.f);
}

extern "C" void kernel_launch(void* const* d_in, const int* in_sizes, int n_in,
                              void* d_out, int out_size, void* d_ws, size_t ws_size,
                              hipStream_t stream) {
  const float* s1     = (const float*)d_in[0];
  const float* s2     = (const float*)d_in[1];
  const float* s3     = (const float*)d_in[2];
  const float* alpha  = (const float*)d_in[3];
  const float* weight = (const float*)d_in[4];
  const float* bias   = (const float*)d_in[5];
  const float* gamma  = (const float*)d_in[6];
  const float* beta   = (const float*)d_in[7];
  float* out = (float*)d_out;

  char* ws = (char*)d_ws;
  float* fused = (float*)ws;                    // 64*448*256*4 = 29,360,128 B
  float* wq    = (float*)(ws + 29360128);       // 128*448*4    =    229,376 B
  float* y     = (float*)(ws + 29589504);       // 64*128*256*4 =  8,388,608 B
  float* stats = (float*)(ws + 37978112);       // 256*4        =      1,024 B

  pool_kernel<<<64 * 448, 256, 0, stream>>>(s1, s2, s3, alpha, fused);
  quant_kernel<<<128, 256, 0, stream>>>(weight, wq);
  dim3 g(4, 2, 64);
  gemm_kernel<<<g, 256, 0, stream>>>(wq, fused, bias, y);
  stats_kernel<<<128, 256, 0, stream>>>(y, stats);
  final_kernel<<<8192, 256, 0, stream>>>(y, stats, gamma, beta, out);
}

// Round 2
// 127.027 us; speedup vs baseline: 1.0346x; 1.0346x over previous
//
#include <hip/hip_runtime.h>

#define EPSV 1e-5f

// ---------------- Kernel 1: adaptive avg pool + softmax(alpha) scale --------
// One block (256 threads) per (b, global-channel) row. Row staged in LDS.
__global__ __launch_bounds__(256) void pool_kernel(
    const float* __restrict__ s1, const float* __restrict__ s2,
    const float* __restrict__ s3, const float* __restrict__ alpha,
    float* __restrict__ fused) {
  __shared__ float row[5000];
  int rid = blockIdx.x;          // 0 .. 64*448-1
  int b = rid / 448;
  int cg = rid % 448;
  const float* src; int C, L, c, widx;
  if (cg < 256)      { src = s1; C = 256; L = 5000; c = cg;       widx = 0; }
  else if (cg < 384) { src = s2; C = 128; L = 2500; c = cg - 256; widx = 1; }
  else               { src = s3; C = 64;  L = 625;  c = cg - 384; widx = 2; }

  float a0 = alpha[0], a1 = alpha[1], a2 = alpha[2];
  float mx = fmaxf(a0, fmaxf(a1, a2));
  float e0 = expf(a0 - mx), e1 = expf(a1 - mx), e2 = expf(a2 - mx);
  float wst = ((widx == 0) ? e0 : (widx == 1) ? e1 : e2) / (e0 + e1 + e2);

  const float* rowp = src + ((size_t)b * C + c) * L;
  if ((L & 3) == 0) {                       // stage1 (5000) & stage2 (2500): 16B-aligned rows
    const float4* rp4 = (const float4*)rowp;
    int L4 = L >> 2;
    for (int i = threadIdx.x; i < L4; i += 256) {
      float4 v = rp4[i];
      int j = i << 2;
      row[j] = v.x; row[j + 1] = v.y; row[j + 2] = v.z; row[j + 3] = v.w;
    }
  } else {                                  // stage3 (625): scalar
    for (int i = threadIdx.x; i < L; i += 256) row[i] = rowp[i];
  }
  __syncthreads();

  int l = threadIdx.x;                       // 256 output positions
  int start = (l * L) >> 8;                  // floor(l*L/256)
  int end = ((l + 1) * L + 255) >> 8;        // ceil((l+1)*L/256)
  float s = 0.f;
  for (int i = start; i < end; ++i) s += row[i];
  fused[((size_t)b * 448 + cg) * 256 + l] = s / (float)(end - start) * wst;
}

// ---------------- Kernel 2: 2-bit weight quantization -----------------------
__global__ __launch_bounds__(256) void quant_kernel(
    const float* __restrict__ w, float* __restrict__ wq) {
  int o = blockIdx.x;            // 128 rows
  int t = threadIdx.x;
  const float* wr = w + o * 448;
  float m = 0.f;
  for (int c = t; c < 448; c += 256) m = fmaxf(m, fabsf(wr[c]));
  __shared__ float sm[4];
  for (int off = 32; off; off >>= 1) m = fmaxf(m, __shfl_down(m, off, 64));
  if ((t & 63) == 0) sm[t >> 6] = m;
  __syncthreads();
  m = fmaxf(fmaxf(sm[0], sm[1]), fmaxf(sm[2], sm[3]));
  float scale = fmaxf(m, 1e-8f);             // qp = 1 for 2-bit symmetric
  for (int c = t; c < 448; c += 256) {
    float q = rintf(wr[c] / scale);          // round-half-even == jnp.round
    q = fminf(fmaxf(q, -2.f), 1.f);
    wq[o * 448 + c] = q * scale;
  }
}

// ---------------- Kernel 3: fp32 tiled GEMM y[b] = wq @ fused[b] + bias -----
// FUSE=1: also emit per-(channel, block) partial sum/sumsq for BatchNorm stats.
#define BM 64
#define BN 64
#define BK 16
template <int FUSE>
__global__ __launch_bounds__(256) void gemm_kernel(
    const float* __restrict__ wq, const float* __restrict__ fused,
    const float* __restrict__ bias, float* __restrict__ y,
    float* __restrict__ Psum, float* __restrict__ Pssq) {
  __shared__ float As[BK][BM + 4];   // [k][m]
  __shared__ float Bs[BK][BN + 4];   // [k][n]
  int b = blockIdx.z;
  int o0 = blockIdx.y * BM;
  int l0 = blockIdx.x * BN;
  const float* Bp = fused + (size_t)b * 448 * 256;
  int tid = threadIdx.x;
  int tx = tid & 15, ty = tid >> 4;
  float acc[4][4] = {};
  for (int c0 = 0; c0 < 448; c0 += BK) {
    {  // A tile: 64x16, 4 consecutive k per thread
      int m = tid >> 2;
      int k = (tid & 3) * 4;
      const float* p = wq + (o0 + m) * 448 + c0 + k;
      As[k][m] = p[0]; As[k + 1][m] = p[1]; As[k + 2][m] = p[2]; As[k + 3][m] = p[3];
    }
    {  // B tile: 16x64, coalesced rows
      #pragma unroll
      for (int i = 0; i < 4; ++i) {
        int e = tid + 256 * i;
        int n = e & 63, k = e >> 6;
        Bs[k][n] = Bp[(size_t)(c0 + k) * 256 + l0 + n];
      }
    }
    __syncthreads();
    #pragma unroll
    for (int k = 0; k < BK; ++k) {
      float a[4], bb[4];
      #pragma unroll
      for (int i = 0; i < 4; ++i) a[i] = As[k][ty * 4 + i];
      #pragma unroll
      for (int j = 0; j < 4; ++j) bb[j] = Bs[k][tx * 4 + j];
      #pragma unroll
      for (int i = 0; i < 4; ++i)
        #pragma unroll
        for (int j = 0; j < 4; ++j)
          acc[i][j] += a[i] * bb[j];
    }
    __syncthreads();
  }
  float sv[4], qv[4];
  #pragma unroll
  for (int i = 0; i < 4; ++i) {
    float bv = bias[o0 + ty * 4 + i];
    sv[i] = 0.f; qv[i] = 0.f;
    #pragma unroll
    for (int j = 0; j < 4; ++j) {
      float yv = acc[i][j] + bv;
      y[((size_t)b * 128 + o0 + ty * 4 + i) * 256 + l0 + tx * 4 + j] = yv;
      if (FUSE) { sv[i] += yv; qv[i] += yv * yv; }
    }
  }
  if (FUSE) {
    // reduce across the 16 tx lanes (each wave = 4 ty groups of 16 lanes)
    #pragma unroll
    for (int i = 0; i < 4; ++i) {
      #pragma unroll
      for (int m = 1; m < 16; m <<= 1) {
        sv[i] += __shfl_xor(sv[i], m, 64);
        qv[i] += __shfl_xor(qv[i], m, 64);
      }
    }
    if (tx == 0) {
      int pidx = b * 4 + blockIdx.x;   // 0..255 fixed slot -> deterministic
      #pragma unroll
      for (int i = 0; i < 4; ++i) {
        int o = o0 + ty * 4 + i;
        Psum[o * 256 + pidx] = sv[i];
        Pssq[o * 256 + pidx] = qv[i];
      }
    }
  }
}

// ---------------- Kernel 4a: finalize stats from partials -------------------
__global__ __launch_bounds__(256) void finalize_kernel(
    const float* __restrict__ Psum, const float* __restrict__ Pssq,
    float* __restrict__ stats) {
  int o = blockIdx.x;            // 128 channels
  int t = threadIdx.x;           // 256 partials
  float s = Psum[o * 256 + t];
  float q = Pssq[o * 256 + t];
  __shared__ float sb[8];
  for (int m = 32; m; m >>= 1) { s += __shfl_down(s, m, 64); q += __shfl_down(q, m, 64); }
  if ((t & 63) == 0) { sb[t >> 6] = s; sb[4 + (t >> 6)] = q; }
  __syncthreads();
  if (t == 0) {
    s = sb[0] + sb[1] + sb[2] + sb[3];
    q = sb[4] + sb[5] + sb[6] + sb[7];
    float mean = s * (1.f / 16384.f);
    float var = q * (1.f / 16384.f) - mean * mean;
    stats[o] = mean;
    stats[128 + o] = rsqrtf(var + EPSV);
  }
}

// ---------------- Kernel 4b (fallback): per-channel batch stats from y ------
__global__ __launch_bounds__(256) void stats_kernel(
    const float* __restrict__ y, float* __restrict__ stats) {
  int o = blockIdx.x;
  int l = threadIdx.x;
  float s = 0.f, ss = 0.f;
  for (int b = 0; b < 64; ++b) {
    float v = y[((size_t)b * 128 + o) * 256 + l];
    s += v; ss += v * v;
  }
  __shared__ float sbuf[8];
  for (int off = 32; off; off >>= 1) {
    s += __shfl_down(s, off, 64);
    ss += __shfl_down(ss, off, 64);
  }
  if ((l & 63) == 0) { sbuf[l >> 6] = s; sbuf[4 + (l >> 6)] = ss; }
  __syncthreads();
  if (l == 0) {
    s = sbuf[0] + sbuf[1] + sbuf[2] + sbuf[3];
    ss = sbuf[4] + sbuf[5] + sbuf[6] + sbuf[7];
    float mean = s * (1.f / 16384.f);
    float var = ss * (1.f / 16384.f) - mean * mean;
    stats[o] = mean;
    stats[128 + o] = rsqrtf(var + EPSV);
  }
}

// ---------------- Kernel 5: BN apply + ELU + mean over L --------------------
__global__ __launch_bounds__(256) void final_kernel(
    const float* __restrict__ y, const float* __restrict__ stats,
    const float* __restrict__ gamma, const float* __restrict__ beta,
    float* __restrict__ out) {
  int bo = blockIdx.x;           // b*128 + o
  int o = bo & 127;
  int l = threadIdx.x;
  float mean = stats[o], rs = stats[128 + o];
  float g = gamma[o], bt = beta[o];
  float v = y[(size_t)bo * 256 + l];
  float yn = (v - mean) * rs * g + bt;
  float act = yn > 0.f ? yn : expm1f(yn);
  __shared__ float sbuf[4];
  for (int off = 32; off; off >>= 1) act += __shfl_down(act, off, 64);
  if ((l & 63) == 0) sbuf[l >> 6] = act;
  __syncthreads();
  if (l == 0) out[bo] = (sbuf[0] + sbuf[1] + sbuf[2] + sbuf[3]) * (1.f / 256.f);
}

extern "C" void kernel_launch(void* const* d_in, const int* in_sizes, int n_in,
                              void* d_out, int out_size, void* d_ws, size_t ws_size,
                              hipStream_t stream) {
  const float* s1     = (const float*)d_in[0];
  const float* s2     = (const float*)d_in[1];
  const float* s3     = (const float*)d_in[2];
  const float* alpha  = (const float*)d_in[3];
  const float* weight = (const float*)d_in[4];
  const float* bias   = (const float*)d_in[5];
  const float* gamma  = (const float*)d_in[6];
  const float* beta   = (const float*)d_in[7];
  float* out = (float*)d_out;

  char* ws = (char*)d_ws;
  float* fused = (float*)ws;                    // 64*448*256*4 = 29,360,128 B
  float* wq    = (float*)(ws + 29360128);       // 128*448*4    =    229,376 B
  float* y     = (float*)(ws + 29589504);       // 64*128*256*4 =  8,388,608 B
  float* stats = (float*)(ws + 37978112);       // 256*4        =      1,024 B
  float* Psum  = (float*)(ws + 37979136);       // 128*256*4    =    131,072 B
  float* Pssq  = (float*)(ws + 38110208);       // 128*256*4    =    131,072 B
  const size_t NEED_FUSED = 38241280;
  bool fuseStats = ws_size >= NEED_FUSED;

  pool_kernel<<<64 * 448, 256, 0, stream>>>(s1, s2, s3, alpha, fused);
  quant_kernel<<<128, 256, 0, stream>>>(weight, wq);
  dim3 g(4, 2, 64);
  if (fuseStats) {
    gemm_kernel<1><<<g, 256, 0, stream>>>(wq, fused, bias, y, Psum, Pssq);
    finalize_kernel<<<128, 256, 0, stream>>>(Psum, Pssq, stats);
  } else {
    gemm_kernel<0><<<g, 256, 0, stream>>>(wq, fused, bias, y, nullptr, nullptr);
    stats_kernel<<<128, 256, 0, stream>>>(y, stats);
  }
  final_kernel<<<8192, 256, 0, stream>>>(y, stats, gamma, beta, out);
}

// Round 3
// 111.548 us; speedup vs baseline: 1.1782x; 1.1388x over previous
//
#include <hip/hip_runtime.h>
#include <hip/hip_bf16.h>

#define EPSV 1e-5f

typedef __attribute__((ext_vector_type(8))) short short8v;
typedef __attribute__((ext_vector_type(4))) float float4v;

__device__ inline unsigned short f2bf(float x) {
  __hip_bfloat16 h = __float2bfloat16(x);   // RNE
  return *reinterpret_cast<unsigned short*>(&h);
}
__device__ inline float bf2f(unsigned short b) {
  unsigned u = ((unsigned)b) << 16;
  float f;
  __builtin_memcpy(&f, &u, 4);
  return f;
}

// ---------------- Kernel 1: adaptive avg pool + softmax(alpha) scale --------
// PACK=1: emit (bf16_hi<<16)|bf16_lo packed u32. PACK=0: plain f32.
template <int PACK>
__global__ __launch_bounds__(256) void pool_kernel(
    const float* __restrict__ s1, const float* __restrict__ s2,
    const float* __restrict__ s3, const float* __restrict__ alpha,
    void* __restrict__ fused_out) {
  __shared__ float row[5000];
  int rid = blockIdx.x;          // 0 .. 64*448-1
  int b = rid / 448;
  int cg = rid % 448;
  const float* src; int C, L, c, widx;
  if (cg < 256)      { src = s1; C = 256; L = 5000; c = cg;       widx = 0; }
  else if (cg < 384) { src = s2; C = 128; L = 2500; c = cg - 256; widx = 1; }
  else               { src = s3; C = 64;  L = 625;  c = cg - 384; widx = 2; }

  float a0 = alpha[0], a1 = alpha[1], a2 = alpha[2];
  float mx = fmaxf(a0, fmaxf(a1, a2));
  float e0 = expf(a0 - mx), e1 = expf(a1 - mx), e2 = expf(a2 - mx);
  float wst = ((widx == 0) ? e0 : (widx == 1) ? e1 : e2) / (e0 + e1 + e2);

  const float* rowp = src + ((size_t)b * C + c) * L;
  if ((L & 3) == 0) {
    const float4* rp4 = (const float4*)rowp;
    int L4 = L >> 2;
    for (int i = threadIdx.x; i < L4; i += 256) {
      float4 v = rp4[i];
      int j = i << 2;
      row[j] = v.x; row[j + 1] = v.y; row[j + 2] = v.z; row[j + 3] = v.w;
    }
  } else {
    for (int i = threadIdx.x; i < L; i += 256) row[i] = rowp[i];
  }
  __syncthreads();

  int l = threadIdx.x;
  int start = (l * L) >> 8;
  int end = ((l + 1) * L + 255) >> 8;
  float s = 0.f;
  for (int i = start; i < end; ++i) s += row[i];
  float v = s / (float)(end - start) * wst;
  size_t oidx = ((size_t)b * 448 + cg) * 256 + l;
  if (PACK) {
    unsigned short hb = f2bf(v);
    float hf = bf2f(hb);
    unsigned short lb = f2bf(v - hf);
    ((unsigned*)fused_out)[oidx] = (((unsigned)hb) << 16) | lb;
  } else {
    ((float*)fused_out)[oidx] = v;
  }
}

// ---------------- Kernel 2: 2-bit quant -> exact bf16 q + f32 scale ---------
__global__ __launch_bounds__(256) void quant_bf_kernel(
    const float* __restrict__ w, unsigned short* __restrict__ qbf,
    float* __restrict__ scales) {
  int o = blockIdx.x;
  int t = threadIdx.x;
  const float* wr = w + o * 448;
  float m = 0.f;
  for (int c = t; c < 448; c += 256) m = fmaxf(m, fabsf(wr[c]));
  __shared__ float sm[4];
  for (int off = 32; off; off >>= 1) m = fmaxf(m, __shfl_down(m, off, 64));
  if ((t & 63) == 0) sm[t >> 6] = m;
  __syncthreads();
  m = fmaxf(fmaxf(sm[0], sm[1]), fmaxf(sm[2], sm[3]));
  float scale = fmaxf(m, 1e-8f);
  for (int c = t; c < 448; c += 256) {
    float q = rintf(wr[c] / scale);
    q = fminf(fmaxf(q, -2.f), 1.f);
    qbf[o * 448 + c] = f2bf(q);        // q in {-2,-1,0,1}: exact in bf16
  }
  if (t == 0) scales[o] = scale;
}

// legacy f32 quant (fallback)
__global__ __launch_bounds__(256) void quant_kernel(
    const float* __restrict__ w, float* __restrict__ wq) {
  int o = blockIdx.x;
  int t = threadIdx.x;
  const float* wr = w + o * 448;
  float m = 0.f;
  for (int c = t; c < 448; c += 256) m = fmaxf(m, fabsf(wr[c]));
  __shared__ float sm[4];
  for (int off = 32; off; off >>= 1) m = fmaxf(m, __shfl_down(m, off, 64));
  if ((t & 63) == 0) sm[t >> 6] = m;
  __syncthreads();
  m = fmaxf(fmaxf(sm[0], sm[1]), fmaxf(sm[2], sm[3]));
  float scale = fmaxf(m, 1e-8f);
  for (int c = t; c < 448; c += 256) {
    float q = rintf(wr[c] / scale);
    q = fminf(fmaxf(q, -2.f), 1.f);
    wq[o * 448 + c] = q * scale;
  }
}

// ---------------- Kernel 3: MFMA GEMM y[b] = scale*(q @ (fhi+flo)) + bias ---
// Block: 256 thr (4 waves as 2x2), 64x64 output tile, K-step 32.
__global__ __launch_bounds__(256) void mfma_gemm_kernel(
    const unsigned short* __restrict__ qbf, const float* __restrict__ scales,
    const unsigned* __restrict__ fusedp, const float* __restrict__ bias,
    float* __restrict__ y, float* __restrict__ Psum, float* __restrict__ Pssq) {
  __shared__ __align__(16) unsigned short Asm[64][40];   // [row][k] pad->80B stride
  __shared__ unsigned Bsm[32][65];                       // [k][n] packed hi/lo
  int b = blockIdx.z;
  int o0 = blockIdx.y * 64;
  int l0 = blockIdx.x * 64;
  int tid = threadIdx.x;
  int wave = tid >> 6, lane = tid & 63;
  int wm = wave >> 1, wn = wave & 1;
  int lrow = lane & 15, lg = lane >> 4;
  const unsigned* Fp = fusedp + (size_t)b * 448 * 256;

  float4v acc[2][2];
  #pragma unroll
  for (int i = 0; i < 2; ++i)
    #pragma unroll
    for (int j = 0; j < 2; ++j)
      acc[i][j] = (float4v){0.f, 0.f, 0.f, 0.f};

  for (int c0 = 0; c0 < 448; c0 += 32) {
    {  // stage A: 64 rows x 32 k bf16
      int r = tid >> 2, k0 = (tid & 3) * 8;
      short8v v = *(const short8v*)(qbf + (size_t)(o0 + r) * 448 + c0 + k0);
      *(short8v*)&Asm[r][k0] = v;
    }
    {  // stage B: 32 k x 64 n packed u32
      int k = tid >> 3, n0 = (tid & 7) * 8;
      const unsigned* gp = Fp + (size_t)(c0 + k) * 256 + l0 + n0;
      uint4 v0 = *(const uint4*)gp;
      uint4 v1 = *(const uint4*)(gp + 4);
      Bsm[k][n0 + 0] = v0.x; Bsm[k][n0 + 1] = v0.y;
      Bsm[k][n0 + 2] = v0.z; Bsm[k][n0 + 3] = v0.w;
      Bsm[k][n0 + 4] = v1.x; Bsm[k][n0 + 5] = v1.y;
      Bsm[k][n0 + 6] = v1.z; Bsm[k][n0 + 7] = v1.w;
    }
    __syncthreads();

    short8v af[2];
    #pragma unroll
    for (int mf = 0; mf < 2; ++mf)
      af[mf] = *(const short8v*)&Asm[wm * 32 + mf * 16 + lrow][lg * 8];

    #pragma unroll
    for (int nf = 0; nf < 2; ++nf) {
      int n = wn * 32 + nf * 16 + lrow;
      unsigned pk[8];
      #pragma unroll
      for (int j = 0; j < 8; ++j) pk[j] = Bsm[lg * 8 + j][n];
      short8v bh, bl;
      #pragma unroll
      for (int j = 0; j < 8; ++j) {
        bh[j] = (short)(pk[j] >> 16);
        bl[j] = (short)(pk[j] & 0xffffu);
      }
      #pragma unroll
      for (int mf = 0; mf < 2; ++mf) {
        acc[mf][nf] = __builtin_amdgcn_mfma_f32_16x16x32_bf16(af[mf], bh, acc[mf][nf], 0, 0, 0);
        acc[mf][nf] = __builtin_amdgcn_mfma_f32_16x16x32_bf16(af[mf], bl, acc[mf][nf], 0, 0, 0);
      }
    }
    __syncthreads();
  }

  // epilogue: scale, bias, store y, partial BN stats
  float sv[2][4], qv[2][4];
  #pragma unroll
  for (int mf = 0; mf < 2; ++mf) {
    #pragma unroll
    for (int reg = 0; reg < 4; ++reg) {
      int r = o0 + wm * 32 + mf * 16 + lg * 4 + reg;
      float sc = scales[r], bv = bias[r];
      float s = 0.f, q = 0.f;
      #pragma unroll
      for (int nf = 0; nf < 2; ++nf) {
        int col = l0 + wn * 32 + nf * 16 + lrow;
        float val = acc[mf][nf][reg] * sc + bv;
        y[((size_t)b * 128 + r) * 256 + col] = val;
        s += val; q += val * val;
      }
      sv[mf][reg] = s; qv[mf][reg] = q;
    }
  }
  #pragma unroll
  for (int mf = 0; mf < 2; ++mf)
    #pragma unroll
    for (int reg = 0; reg < 4; ++reg) {
      #pragma unroll
      for (int m = 1; m < 16; m <<= 1) {
        sv[mf][reg] += __shfl_xor(sv[mf][reg], m, 64);
        qv[mf][reg] += __shfl_xor(qv[mf][reg], m, 64);
      }
    }
  if (lrow == 0) {
    int slot = b * 8 + blockIdx.x * 2 + wn;   // 0..511, unique per (b,ntile,wn)
    #pragma unroll
    for (int mf = 0; mf < 2; ++mf)
      #pragma unroll
      for (int reg = 0; reg < 4; ++reg) {
        int r = o0 + wm * 32 + mf * 16 + lg * 4 + reg;
        Psum[r * 512 + slot] = sv[mf][reg];
        Pssq[r * 512 + slot] = qv[mf][reg];
      }
  }
}

// legacy fp32 GEMM (fallback)
#define BM 64
#define BN 64
#define BK 16
__global__ __launch_bounds__(256) void gemm_kernel(
    const float* __restrict__ wq, const float* __restrict__ fused,
    const float* __restrict__ bias, float* __restrict__ y) {
  __shared__ float As[BK][BM + 4];
  __shared__ float Bs[BK][BN + 4];
  int b = blockIdx.z;
  int o0 = blockIdx.y * BM;
  int l0 = blockIdx.x * BN;
  const float* Bp = fused + (size_t)b * 448 * 256;
  int tid = threadIdx.x;
  int tx = tid & 15, ty = tid >> 4;
  float acc[4][4] = {};
  for (int c0 = 0; c0 < 448; c0 += BK) {
    {
      int m = tid >> 2;
      int k = (tid & 3) * 4;
      const float* p = wq + (o0 + m) * 448 + c0 + k;
      As[k][m] = p[0]; As[k + 1][m] = p[1]; As[k + 2][m] = p[2]; As[k + 3][m] = p[3];
    }
    {
      #pragma unroll
      for (int i = 0; i < 4; ++i) {
        int e = tid + 256 * i;
        int n = e & 63, k = e >> 6;
        Bs[k][n] = Bp[(size_t)(c0 + k) * 256 + l0 + n];
      }
    }
    __syncthreads();
    #pragma unroll
    for (int k = 0; k < BK; ++k) {
      float a[4], bb[4];
      #pragma unroll
      for (int i = 0; i < 4; ++i) a[i] = As[k][ty * 4 + i];
      #pragma unroll
      for (int j = 0; j < 4; ++j) bb[j] = Bs[k][tx * 4 + j];
      #pragma unroll
      for (int i = 0; i < 4; ++i)
        #pragma unroll
        for (int j = 0; j < 4; ++j)
          acc[i][j] += a[i] * bb[j];
    }
    __syncthreads();
  }
  #pragma unroll
  for (int i = 0; i < 4; ++i) {
    float bv = bias[o0 + ty * 4 + i];
    #pragma unroll
    for (int j = 0; j < 4; ++j)
      y[((size_t)b * 128 + o0 + ty * 4 + i) * 256 + l0 + tx * 4 + j] = acc[i][j] + bv;
  }
}

// ---------------- Kernel 4a: finalize stats from 512 partials/channel -------
__global__ __launch_bounds__(256) void finalize_kernel(
    const float* __restrict__ Psum, const float* __restrict__ Pssq,
    float* __restrict__ stats) {
  int o = blockIdx.x;
  int t = threadIdx.x;
  float s = Psum[o * 512 + t] + Psum[o * 512 + 256 + t];
  float q = Pssq[o * 512 + t] + Pssq[o * 512 + 256 + t];
  __shared__ float sb[8];
  for (int m = 32; m; m >>= 1) { s += __shfl_down(s, m, 64); q += __shfl_down(q, m, 64); }
  if ((t & 63) == 0) { sb[t >> 6] = s; sb[4 + (t >> 6)] = q; }
  __syncthreads();
  if (t == 0) {
    s = sb[0] + sb[1] + sb[2] + sb[3];
    q = sb[4] + sb[5] + sb[6] + sb[7];
    float mean = s * (1.f / 16384.f);
    float var = q * (1.f / 16384.f) - mean * mean;
    stats[o] = mean;
    stats[128 + o] = rsqrtf(var + EPSV);
  }
}

// fallback stats from y
__global__ __launch_bounds__(256) void stats_kernel(
    const float* __restrict__ y, float* __restrict__ stats) {
  int o = blockIdx.x;
  int l = threadIdx.x;
  float s = 0.f, ss = 0.f;
  for (int b = 0; b < 64; ++b) {
    float v = y[((size_t)b * 128 + o) * 256 + l];
    s += v; ss += v * v;
  }
  __shared__ float sbuf[8];
  for (int off = 32; off; off >>= 1) {
    s += __shfl_down(s, off, 64);
    ss += __shfl_down(ss, off, 64);
  }
  if ((l & 63) == 0) { sbuf[l >> 6] = s; sbuf[4 + (l >> 6)] = ss; }
  __syncthreads();
  if (l == 0) {
    s = sbuf[0] + sbuf[1] + sbuf[2] + sbuf[3];
    ss = sbuf[4] + sbuf[5] + sbuf[6] + sbuf[7];
    float mean = s * (1.f / 16384.f);
    float var = ss * (1.f / 16384.f) - mean * mean;
    stats[o] = mean;
    stats[128 + o] = rsqrtf(var + EPSV);
  }
}

// ---------------- Kernel 5: BN apply + ELU + mean over L (1 wave / row) -----
__global__ __launch_bounds__(256) void final_kernel(
    const float* __restrict__ y, const float* __restrict__ stats,
    const float* __restrict__ gamma, const float* __restrict__ beta,
    float* __restrict__ out) {
  int w = threadIdx.x >> 6;
  int lane = threadIdx.x & 63;
  int bo = blockIdx.x * 4 + w;     // b*128 + o
  int o = bo & 127;
  float mean = stats[o], rs = stats[128 + o];
  float g = gamma[o], bt = beta[o];
  float4 v = *(const float4*)(y + (size_t)bo * 256 + lane * 4);
  float acc = 0.f;
  #pragma unroll
  for (int j = 0; j < 4; ++j) {
    float e = (&v.x)[j];
    float yn = (e - mean) * rs * g + bt;
    acc += yn > 0.f ? yn : expm1f(yn);
  }
  for (int m = 32; m; m >>= 1) acc += __shfl_down(acc, m, 64);
  if (lane == 0) out[bo] = acc * (1.f / 256.f);
}

extern "C" void kernel_launch(void* const* d_in, const int* in_sizes, int n_in,
                              void* d_out, int out_size, void* d_ws, size_t ws_size,
                              hipStream_t stream) {
  const float* s1     = (const float*)d_in[0];
  const float* s2     = (const float*)d_in[1];
  const float* s3     = (const float*)d_in[2];
  const float* alpha  = (const float*)d_in[3];
  const float* weight = (const float*)d_in[4];
  const float* bias   = (const float*)d_in[5];
  const float* gamma  = (const float*)d_in[6];
  const float* beta   = (const float*)d_in[7];
  float* out = (float*)d_out;

  char* ws = (char*)d_ws;
  // MFMA-path layout
  unsigned* fusedp       = (unsigned*)ws;                    // 29,360,128
  unsigned short* qbf    = (unsigned short*)(ws + 29360128); //    114,688
  float* scales          = (float*)(ws + 29474816);          //        512
  float* y               = (float*)(ws + 29475328);          //  8,388,608
  float* stats           = (float*)(ws + 37863936);          //      1,024
  float* Psum            = (float*)(ws + 37864960);          //    262,144
  float* Pssq            = (float*)(ws + 38127104);          //    262,144
  const size_t NEED_MFMA = 38389248;

  if (ws_size >= NEED_MFMA) {
    pool_kernel<1><<<64 * 448, 256, 0, stream>>>(s1, s2, s3, alpha, fusedp);
    quant_bf_kernel<<<128, 256, 0, stream>>>(weight, qbf, scales);
    dim3 g(4, 2, 64);
    mfma_gemm_kernel<<<g, 256, 0, stream>>>(qbf, scales, fusedp, bias, y, Psum, Pssq);
    finalize_kernel<<<128, 256, 0, stream>>>(Psum, Pssq, stats);
    final_kernel<<<2048, 256, 0, stream>>>(y, stats, gamma, beta, out);
  } else {
    // fallback: fp32 path
    float* fused = (float*)ws;                    // 29,360,128
    float* wq    = (float*)(ws + 29360128);       //    229,376
    float* yf    = (float*)(ws + 29589504);       //  8,388,608
    float* st    = (float*)(ws + 37978112);       //      1,024
    pool_kernel<0><<<64 * 448, 256, 0, stream>>>(s1, s2, s3, alpha, fused);
    quant_kernel<<<128, 256, 0, stream>>>(weight, wq);
    dim3 g(4, 2, 64);
    gemm_kernel<<<g, 256, 0, stream>>>(wq, fused, bias, yf);
    stats_kernel<<<128, 256, 0, stream>>>(yf, st);
    final_kernel<<<2048, 256, 0, stream>>>(yf, st, gamma, beta, out);
  }
}

// Round 4
// 108.665 us; speedup vs baseline: 1.2095x; 1.0265x over previous
//
#include <hip/hip_runtime.h>
#include <hip/hip_bf16.h>

#define EPSV 1e-5f

typedef __attribute__((ext_vector_type(8))) short short8v;
typedef __attribute__((ext_vector_type(4))) float float4v;

__device__ inline unsigned short f2bf(float x) {
  __hip_bfloat16 h = __float2bfloat16(x);   // RNE
  return *reinterpret_cast<unsigned short*>(&h);
}

// ---------------- Kernel 1: adaptive avg pool + softmax(alpha) scale --------
// BF=1: emit bf16. BF=0: plain f32 (fallback).
template <int BF>
__global__ __launch_bounds__(256) void pool_kernel(
    const float* __restrict__ s1, const float* __restrict__ s2,
    const float* __restrict__ s3, const float* __restrict__ alpha,
    void* __restrict__ fused_out) {
  __shared__ float row[5000];
  int rid = blockIdx.x;          // 0 .. 64*448-1
  int b = rid / 448;
  int cg = rid % 448;
  const float* src; int C, L, c, widx;
  if (cg < 256)      { src = s1; C = 256; L = 5000; c = cg;       widx = 0; }
  else if (cg < 384) { src = s2; C = 128; L = 2500; c = cg - 256; widx = 1; }
  else               { src = s3; C = 64;  L = 625;  c = cg - 384; widx = 2; }

  float a0 = alpha[0], a1 = alpha[1], a2 = alpha[2];
  float mx = fmaxf(a0, fmaxf(a1, a2));
  float e0 = expf(a0 - mx), e1 = expf(a1 - mx), e2 = expf(a2 - mx);
  float wst = ((widx == 0) ? e0 : (widx == 1) ? e1 : e2) / (e0 + e1 + e2);

  const float* rowp = src + ((size_t)b * C + c) * L;
  if ((L & 3) == 0) {
    const float4* rp4 = (const float4*)rowp;
    int L4 = L >> 2;
    for (int i = threadIdx.x; i < L4; i += 256) {
      float4 v = rp4[i];
      int j = i << 2;
      row[j] = v.x; row[j + 1] = v.y; row[j + 2] = v.z; row[j + 3] = v.w;
    }
  } else {
    for (int i = threadIdx.x; i < L; i += 256) row[i] = rowp[i];
  }
  __syncthreads();

  int l = threadIdx.x;
  int start = (l * L) >> 8;
  int end = ((l + 1) * L + 255) >> 8;
  float s = 0.f;
  for (int i = start; i < end; ++i) s += row[i];
  float v = s / (float)(end - start) * wst;
  size_t oidx = ((size_t)b * 448 + cg) * 256 + l;
  if (BF) {
    ((unsigned short*)fused_out)[oidx] = f2bf(v);
  } else {
    ((float*)fused_out)[oidx] = v;
  }
}

// ---------------- Kernel 2: 2-bit quant -> exact bf16 q + f32 scale ---------
__global__ __launch_bounds__(256) void quant_bf_kernel(
    const float* __restrict__ w, unsigned short* __restrict__ qbf,
    float* __restrict__ scales) {
  int o = blockIdx.x;
  int t = threadIdx.x;
  const float* wr = w + o * 448;
  float m = 0.f;
  for (int c = t; c < 448; c += 256) m = fmaxf(m, fabsf(wr[c]));
  __shared__ float sm[4];
  for (int off = 32; off; off >>= 1) m = fmaxf(m, __shfl_down(m, off, 64));
  if ((t & 63) == 0) sm[t >> 6] = m;
  __syncthreads();
  m = fmaxf(fmaxf(sm[0], sm[1]), fmaxf(sm[2], sm[3]));
  float scale = fmaxf(m, 1e-8f);
  for (int c = t; c < 448; c += 256) {
    float q = rintf(wr[c] / scale);
    q = fminf(fmaxf(q, -2.f), 1.f);
    qbf[o * 448 + c] = f2bf(q);        // q in {-2,-1,0,1}: exact in bf16
  }
  if (t == 0) scales[o] = scale;
}

// legacy f32 quant (fallback)
__global__ __launch_bounds__(256) void quant_kernel(
    const float* __restrict__ w, float* __restrict__ wq) {
  int o = blockIdx.x;
  int t = threadIdx.x;
  const float* wr = w + o * 448;
  float m = 0.f;
  for (int c = t; c < 448; c += 256) m = fmaxf(m, fabsf(wr[c]));
  __shared__ float sm[4];
  for (int off = 32; off; off >>= 1) m = fmaxf(m, __shfl_down(m, off, 64));
  if ((t & 63) == 0) sm[t >> 6] = m;
  __syncthreads();
  m = fmaxf(fmaxf(sm[0], sm[1]), fmaxf(sm[2], sm[3]));
  float scale = fmaxf(m, 1e-8f);
  for (int c = t; c < 448; c += 256) {
    float q = rintf(wr[c] / scale);
    q = fminf(fmaxf(q, -2.f), 1.f);
    wq[o * 448 + c] = q * scale;
  }
}

// ---------------- Kernel 3: MFMA GEMM y[b] = scale*(q @ f_bf16) + bias ------
// Block: 256 thr (4 waves as 2x2), 64x64 output tile, K-step 32, single pass.
__global__ __launch_bounds__(256) void mfma_gemm_kernel(
    const unsigned short* __restrict__ qbf, const float* __restrict__ scales,
    const unsigned short* __restrict__ fusedb, const float* __restrict__ bias,
    float* __restrict__ y, float* __restrict__ Psum, float* __restrict__ Pssq) {
  __shared__ __align__(16) unsigned short Asm[64][40];   // [row][k]
  __shared__ __align__(16) unsigned short Bsm[32][66];   // [k][n]
  int b = blockIdx.z;
  int o0 = blockIdx.y * 64;
  int l0 = blockIdx.x * 64;
  int tid = threadIdx.x;
  int wave = tid >> 6, lane = tid & 63;
  int wm = wave >> 1, wn = wave & 1;
  int lrow = lane & 15, lg = lane >> 4;
  const unsigned short* Fp = fusedb + (size_t)b * 448 * 256;

  float4v acc[2][2];
  #pragma unroll
  for (int i = 0; i < 2; ++i)
    #pragma unroll
    for (int j = 0; j < 2; ++j)
      acc[i][j] = (float4v){0.f, 0.f, 0.f, 0.f};

  for (int c0 = 0; c0 < 448; c0 += 32) {
    {  // stage A: 64 rows x 32 k bf16
      int r = tid >> 2, k0 = (tid & 3) * 8;
      short8v v = *(const short8v*)(qbf + (size_t)(o0 + r) * 448 + c0 + k0);
      *(short8v*)&Asm[r][k0] = v;
    }
    {  // stage B: 32 k x 64 n bf16 (each thread: contiguous 8 along n)
      int k = tid >> 3, n0 = (tid & 7) * 8;
      short8v v = *(const short8v*)(Fp + (size_t)(c0 + k) * 256 + l0 + n0);
      *(short8v*)&Bsm[k][n0] = v;
    }
    __syncthreads();

    short8v af[2];
    #pragma unroll
    for (int mf = 0; mf < 2; ++mf)
      af[mf] = *(const short8v*)&Asm[wm * 32 + mf * 16 + lrow][lg * 8];

    #pragma unroll
    for (int nf = 0; nf < 2; ++nf) {
      int n = wn * 32 + nf * 16 + lrow;
      short8v bf;
      #pragma unroll
      for (int j = 0; j < 8; ++j) bf[j] = (short)Bsm[lg * 8 + j][n];
      #pragma unroll
      for (int mf = 0; mf < 2; ++mf)
        acc[mf][nf] = __builtin_amdgcn_mfma_f32_16x16x32_bf16(af[mf], bf, acc[mf][nf], 0, 0, 0);
    }
    __syncthreads();
  }

  // epilogue: scale, bias, store y, partial BN stats
  float sv[2][4], qv[2][4];
  #pragma unroll
  for (int mf = 0; mf < 2; ++mf) {
    #pragma unroll
    for (int reg = 0; reg < 4; ++reg) {
      int r = o0 + wm * 32 + mf * 16 + lg * 4 + reg;
      float sc = scales[r], bv = bias[r];
      float s = 0.f, q = 0.f;
      #pragma unroll
      for (int nf = 0; nf < 2; ++nf) {
        int col = l0 + wn * 32 + nf * 16 + lrow;
        float val = acc[mf][nf][reg] * sc + bv;
        y[((size_t)b * 128 + r) * 256 + col] = val;
        s += val; q += val * val;
      }
      sv[mf][reg] = s; qv[mf][reg] = q;
    }
  }
  #pragma unroll
  for (int mf = 0; mf < 2; ++mf)
    #pragma unroll
    for (int reg = 0; reg < 4; ++reg) {
      #pragma unroll
      for (int m = 1; m < 16; m <<= 1) {
        sv[mf][reg] += __shfl_xor(sv[mf][reg], m, 64);
        qv[mf][reg] += __shfl_xor(qv[mf][reg], m, 64);
      }
    }
  if (lrow == 0) {
    int slot = b * 8 + blockIdx.x * 2 + wn;   // 0..511 fixed slot
    #pragma unroll
    for (int mf = 0; mf < 2; ++mf)
      #pragma unroll
      for (int reg = 0; reg < 4; ++reg) {
        int r = o0 + wm * 32 + mf * 16 + lg * 4 + reg;
        Psum[r * 512 + slot] = sv[mf][reg];
        Pssq[r * 512 + slot] = qv[mf][reg];
      }
  }
}

// legacy fp32 GEMM (fallback)
#define BM 64
#define BN 64
#define BK 16
__global__ __launch_bounds__(256) void gemm_kernel(
    const float* __restrict__ wq, const float* __restrict__ fused,
    const float* __restrict__ bias, float* __restrict__ y) {
  __shared__ float As[BK][BM + 4];
  __shared__ float Bs[BK][BN + 4];
  int b = blockIdx.z;
  int o0 = blockIdx.y * BM;
  int l0 = blockIdx.x * BN;
  const float* Bp = fused + (size_t)b * 448 * 256;
  int tid = threadIdx.x;
  int tx = tid & 15, ty = tid >> 4;
  float acc[4][4] = {};
  for (int c0 = 0; c0 < 448; c0 += BK) {
    {
      int m = tid >> 2;
      int k = (tid & 3) * 4;
      const float* p = wq + (o0 + m) * 448 + c0 + k;
      As[k][m] = p[0]; As[k + 1][m] = p[1]; As[k + 2][m] = p[2]; As[k + 3][m] = p[3];
    }
    {
      #pragma unroll
      for (int i = 0; i < 4; ++i) {
        int e = tid + 256 * i;
        int n = e & 63, k = e >> 6;
        Bs[k][n] = Bp[(size_t)(c0 + k) * 256 + l0 + n];
      }
    }
    __syncthreads();
    #pragma unroll
    for (int k = 0; k < BK; ++k) {
      float a[4], bb[4];
      #pragma unroll
      for (int i = 0; i < 4; ++i) a[i] = As[k][ty * 4 + i];
      #pragma unroll
      for (int j = 0; j < 4; ++j) bb[j] = Bs[k][tx * 4 + j];
      #pragma unroll
      for (int i = 0; i < 4; ++i)
        #pragma unroll
        for (int j = 0; j < 4; ++j)
          acc[i][j] += a[i] * bb[j];
    }
    __syncthreads();
  }
  #pragma unroll
  for (int i = 0; i < 4; ++i) {
    float bv = bias[o0 + ty * 4 + i];
    #pragma unroll
    for (int j = 0; j < 4; ++j)
      y[((size_t)b * 128 + o0 + ty * 4 + i) * 256 + l0 + tx * 4 + j] = acc[i][j] + bv;
  }
}

// ---------------- Kernel 4a: finalize stats from 512 partials/channel -------
__global__ __launch_bounds__(256) void finalize_kernel(
    const float* __restrict__ Psum, const float* __restrict__ Pssq,
    float* __restrict__ stats) {
  int o = blockIdx.x;
  int t = threadIdx.x;
  float s = Psum[o * 512 + t] + Psum[o * 512 + 256 + t];
  float q = Pssq[o * 512 + t] + Pssq[o * 512 + 256 + t];
  __shared__ float sb[8];
  for (int m = 32; m; m >>= 1) { s += __shfl_down(s, m, 64); q += __shfl_down(q, m, 64); }
  if ((t & 63) == 0) { sb[t >> 6] = s; sb[4 + (t >> 6)] = q; }
  __syncthreads();
  if (t == 0) {
    s = sb[0] + sb[1] + sb[2] + sb[3];
    q = sb[4] + sb[5] + sb[6] + sb[7];
    float mean = s * (1.f / 16384.f);
    float var = q * (1.f / 16384.f) - mean * mean;
    stats[o] = mean;
    stats[128 + o] = rsqrtf(var + EPSV);
  }
}

// fallback stats from y
__global__ __launch_bounds__(256) void stats_kernel(
    const float* __restrict__ y, float* __restrict__ stats) {
  int o = blockIdx.x;
  int l = threadIdx.x;
  float s = 0.f, ss = 0.f;
  for (int b = 0; b < 64; ++b) {
    float v = y[((size_t)b * 128 + o) * 256 + l];
    s += v; ss += v * v;
  }
  __shared__ float sbuf[8];
  for (int off = 32; off; off >>= 1) {
    s += __shfl_down(s, off, 64);
    ss += __shfl_down(ss, off, 64);
  }
  if ((l & 63) == 0) { sbuf[l >> 6] = s; sbuf[4 + (l >> 6)] = ss; }
  __syncthreads();
  if (l == 0) {
    s = sbuf[0] + sbuf[1] + sbuf[2] + sbuf[3];
    ss = sbuf[4] + sbuf[5] + sbuf[6] + sbuf[7];
    float mean = s * (1.f / 16384.f);
    float var = ss * (1.f / 16384.f) - mean * mean;
    stats[o] = mean;
    stats[128 + o] = rsqrtf(var + EPSV);
  }
}

// ---------------- Kernel 5: BN apply + ELU + mean over L (1 wave / row) -----
__global__ __launch_bounds__(256) void final_kernel(
    const float* __restrict__ y, const float* __restrict__ stats,
    const float* __restrict__ gamma, const float* __restrict__ beta,
    float* __restrict__ out) {
  int w = threadIdx.x >> 6;
  int lane = threadIdx.x & 63;
  int bo = blockIdx.x * 4 + w;     // b*128 + o
  int o = bo & 127;
  float mean = stats[o], rs = stats[128 + o];
  float g = gamma[o], bt = beta[o];
  float4 v = *(const float4*)(y + (size_t)bo * 256 + lane * 4);
  float acc = 0.f;
  #pragma unroll
  for (int j = 0; j < 4; ++j) {
    float e = (&v.x)[j];
    float yn = (e - mean) * rs * g + bt;
    acc += yn > 0.f ? yn : expm1f(yn);
  }
  for (int m = 32; m; m >>= 1) acc += __shfl_down(acc, m, 64);
  if (lane == 0) out[bo] = acc * (1.f / 256.f);
}

extern "C" void kernel_launch(void* const* d_in, const int* in_sizes, int n_in,
                              void* d_out, int out_size, void* d_ws, size_t ws_size,
                              hipStream_t stream) {
  const float* s1     = (const float*)d_in[0];
  const float* s2     = (const float*)d_in[1];
  const float* s3     = (const float*)d_in[2];
  const float* alpha  = (const float*)d_in[3];
  const float* weight = (const float*)d_in[4];
  const float* bias   = (const float*)d_in[5];
  const float* gamma  = (const float*)d_in[6];
  const float* beta   = (const float*)d_in[7];
  float* out = (float*)d_out;

  char* ws = (char*)d_ws;
  // MFMA-path layout
  unsigned short* fusedb = (unsigned short*)ws;              // 14,680,064
  unsigned short* qbf    = (unsigned short*)(ws + 14680064); //    114,688
  float* scales          = (float*)(ws + 14794752);          //        512
  float* y               = (float*)(ws + 14795264);          //  8,388,608
  float* stats           = (float*)(ws + 23183872);          //      1,024
  float* Psum            = (float*)(ws + 23184896);          //    262,144
  float* Pssq            = (float*)(ws + 23447040);          //    262,144
  const size_t NEED_MFMA = 23709184;

  if (ws_size >= NEED_MFMA) {
    pool_kernel<1><<<64 * 448, 256, 0, stream>>>(s1, s2, s3, alpha, fusedb);
    quant_bf_kernel<<<128, 256, 0, stream>>>(weight, qbf, scales);
    dim3 g(4, 2, 64);
    mfma_gemm_kernel<<<g, 256, 0, stream>>>(qbf, scales, fusedb, bias, y, Psum, Pssq);
    finalize_kernel<<<128, 256, 0, stream>>>(Psum, Pssq, stats);
    final_kernel<<<2048, 256, 0, stream>>>(y, stats, gamma, beta, out);
  } else {
    // fallback: fp32 path
    float* fused = (float*)ws;                    // 29,360,128
    float* wq    = (float*)(ws + 29360128);       //    229,376
    float* yf    = (float*)(ws + 29589504);       //  8,388,608
    float* st    = (float*)(ws + 37978112);       //      1,024
    pool_kernel<0><<<64 * 448, 256, 0, stream>>>(s1, s2, s3, alpha, fused);
    quant_kernel<<<128, 256, 0, stream>>>(weight, wq);
    dim3 g(4, 2, 64);
    gemm_kernel<<<g, 256, 0, stream>>>(wq, fused, bias, yf);
    stats_kernel<<<128, 256, 0, stream>>>(yf, st);
    final_kernel<<<2048, 256, 0, stream>>>(yf, st, gamma, beta, out);
  }
}